// Round 5
// baseline (5660.783 us; speedup 1.0000x reference)
//
#include <hip/hip_runtime.h>
#include <hip/hip_fp16.h>
#include <stdint.h>
#include <stddef.h>

#define Bb 64
#define Ss 1024
#define Ii 512
#define Hh 512
#define G4 2048   // 4*H
#define NBK 64    // recurrence blocks
#define JPB 8     // hidden units per block

typedef _Float16 h16;
typedef _Float16 h16x8 __attribute__((ext_vector_type(8)));
typedef float    f32x4 __attribute__((ext_vector_type(4)));
typedef unsigned u32x4 __attribute__((ext_vector_type(4)));   // native, asm-legal

__device__ __forceinline__ float sigm(float x){ return 1.0f / (1.0f + __expf(-x)); }
__device__ __forceinline__ float tanh_(float x){
  float e = __expf(-2.0f * fabsf(x));
  float t = (1.0f - e) / (1.0f + e);
  return copysignf(t, x);
}

// device-coherent accesses: bypass L1+L2, served at device coherence point
__device__ __forceinline__ u32x4 load_coh16(const void* p){
  u32x4 r;
  asm volatile("global_load_dwordx4 %0, %1, off sc0 sc1"
               : "=v"(r) : "v"(p) : "memory");
  return r;
}
__device__ __forceinline__ unsigned load_coh4_wait(const void* p){
  unsigned r;
  asm volatile("global_load_dword %0, %1, off sc0 sc1\n\t"
               "s_waitcnt vmcnt(0)"
               : "=v"(r) : "v"(p) : "memory");
  return r;
}
__device__ __forceinline__ void store_coh4(void* p, unsigned v){
  asm volatile("global_store_dword %0, %1, off sc0 sc1"
               :: "v"(p), "v"(v) : "memory");
}
__device__ __forceinline__ void store_coh2(void* p, unsigned v){
  asm volatile("global_store_short %0, %1, off sc0 sc1"
               :: "v"(p), "v"(v) : "memory");
}
// plain (cacheable) 16B load as volatile asm: cannot be rematerialized
__device__ __forceinline__ u32x4 load_once16(const void* p){
  u32x4 r;
  asm volatile("global_load_dwordx4 %0, %1, off"
               : "=v"(r) : "v"(p) : "memory");
  return r;
}

// ---------------------------------------------------------------------------
// prep 1: WxT[n][k] = (f16) W_xh[k][n] for k < I  (B^T layout for gemm_zx)
// ---------------------------------------------------------------------------
__global__ void prep_weights(const float* __restrict__ Wxh, h16* __restrict__ WxT){
  int idx = blockIdx.x * 256 + threadIdx.x;
  if (idx >= Ii * G4) return;
  int k = idx / G4, n = idx % G4;
  WxT[(size_t)n * Ii + k] = (h16)Wxh[idx];
}

// ---------------------------------------------------------------------------
// prep 2: pack W_h into per-block register-fragment order + init h_buf + flags
// ---------------------------------------------------------------------------
__global__ void prep_rec(const float* __restrict__ Wxh, u32x4* __restrict__ Wr,
                         const float* __restrict__ h0g, h16* __restrict__ hbuf,
                         unsigned* __restrict__ flag){
  int blk = blockIdx.x, tid = threadIdx.x;
  if (blk < 512){
    int d  = blk * 256 + tid;
    int l  = d & 63, pk = (d >> 6) & 31, bk = d >> 11;
    int n  = pk >> 4, ks = pk & 15;
    int k  = ks * 32 + (l >> 4) * 8;
    int cl = n * 16 + (l & 15);
    int col = (cl >> 3) * 512 + bk * JPB + (cl & 7);
    h16x8 v;
    #pragma unroll
    for (int e = 0; e < 8; ++e)
      v[e] = (h16)Wxh[(size_t)(Ii + k + e) * G4 + col];
    Wr[d] = *(u32x4*)&v;
  } else {
    int t = (blk - 512) * 256 + tid;    // 0..1023
    #pragma unroll
    for (int i = 0; i < 32; ++i){
      int idx = t * 32 + i;             // covers 64*512 h16 of buffer 0
      hbuf[idx] = (h16)h0g[idx];
    }
    if (t < NBK) flag[t] = 0;
  }
}

// ---------------------------------------------------------------------------
// zx GEMM (unchanged): zx[r][n] = sum_k x_row(r)[k] * W_x[k][n]
// ---------------------------------------------------------------------------
#define BM 128
#define BN 128
#define BK 32
#define LDP 48

__global__ __launch_bounds__(256) void gemm_zx(const float* __restrict__ x,
                                               const h16* __restrict__ WxT,
                                               float* __restrict__ zx,
                                               int t0, int tclog){
  __shared__ h16 lA[BM][LDP];
  __shared__ h16 lB[BN][LDP];
  const int tid  = threadIdx.x;
  const int lane = tid & 63, wid = tid >> 6;
  const int wm = wid >> 1, wn = wid & 1;
  const int bn0 = blockIdx.x * BN, bm0 = blockIdx.y * BM;

  f32x4 acc[4][4] = {};

  const int r_local = tid >> 1;
  const int kh = (tid & 1) * 16;
  const int r = bm0 + r_local;
  const int bidx = r >> tclog;
  const int sc   = r & ((1 << tclog) - 1);
  const float* xrow = x + ((size_t)bidx * Ss + (t0 + sc)) * Ii + kh;

  for (int ks = 0; ks < Ii / BK; ++ks){
    const int k0 = ks * BK;
    __syncthreads();
    {
      const float* p = xrow + k0;
      f32x4 v0 = *(const f32x4*)(p);
      f32x4 v1 = *(const f32x4*)(p + 4);
      f32x4 v2 = *(const f32x4*)(p + 8);
      f32x4 v3 = *(const f32x4*)(p + 12);
      h16x8 o0, o1;
      o0[0]=(h16)v0[0]; o0[1]=(h16)v0[1]; o0[2]=(h16)v0[2]; o0[3]=(h16)v0[3];
      o0[4]=(h16)v1[0]; o0[5]=(h16)v1[1]; o0[6]=(h16)v1[2]; o0[7]=(h16)v1[3];
      o1[0]=(h16)v2[0]; o1[1]=(h16)v2[1]; o1[2]=(h16)v2[2]; o1[3]=(h16)v2[3];
      o1[4]=(h16)v3[0]; o1[5]=(h16)v3[1]; o1[6]=(h16)v3[2]; o1[7]=(h16)v3[3];
      *(h16x8*)&lA[r_local][kh]     = o0;
      *(h16x8*)&lA[r_local][kh + 8] = o1;
    }
    #pragma unroll
    for (int i = 0; i < 2; ++i){
      int flat = i * 256 + tid;
      int nl = flat >> 2, kq = flat & 3;
      u32x4 w = *(const u32x4*)(WxT + ((size_t)(bn0 + nl)) * Ii + k0 + kq * 8);
      *(u32x4*)&lB[nl][kq * 8] = w;
    }
    __syncthreads();
    h16x8 af[4], bfr[4];
    #pragma unroll
    for (int m = 0; m < 4; ++m)
      af[m] = *(const h16x8*)&lA[wm * 64 + m * 16 + (lane & 15)][(lane >> 4) * 8];
    #pragma unroll
    for (int n = 0; n < 4; ++n)
      bfr[n] = *(const h16x8*)&lB[wn * 64 + n * 16 + (lane & 15)][(lane >> 4) * 8];
    #pragma unroll
    for (int m = 0; m < 4; ++m)
      #pragma unroll
      for (int n = 0; n < 4; ++n)
        acc[m][n] = __builtin_amdgcn_mfma_f32_16x16x32_f16(af[m], bfr[n], acc[m][n], 0, 0, 0);
  }
  #pragma unroll
  for (int m = 0; m < 4; ++m){
    int rg = bm0 + wm * 64 + m * 16 + ((lane >> 4) << 2);
    #pragma unroll
    for (int n = 0; n < 4; ++n){
      int cg = bn0 + wn * 64 + n * 16 + (lane & 15);
      #pragma unroll
      for (int q = 0; q < 4; ++q)
        zx[(size_t)(rg + q) * G4 + cg] = acc[m][n][q];
    }
  }
}

// ---------------------------------------------------------------------------
// Recurrence v4: weights loaded via volatile asm (cannot remat), h exchange
// via coherent 2B stores + per-producer monotonic flag (no atomic RMW),
// all-lane flag poll. 2 barriers/step.
// ---------------------------------------------------------------------------
__global__ __launch_bounds__(256, 1) void lstm_rec2(
    const float* __restrict__ zx, const u32x4* __restrict__ Wr,
    h16* __restrict__ hbuf, unsigned* __restrict__ flag,
    const float* __restrict__ c0g, float* __restrict__ c_state,
    const float* __restrict__ Wci, const float* __restrict__ Wcf, const float* __restrict__ Wco,
    const float* __restrict__ bi, const float* __restrict__ bfg, const float* __restrict__ bc,
    const float* __restrict__ bo,
    float* __restrict__ out, float* __restrict__ hT, float* __restrict__ cT,
    int t0, int Tc, int first, int last)
{
  __shared__ float zf[64 * 33];
  __shared__ float szp[64 * 36];

  const int bk = blockIdx.x, tid = threadIdx.x;
  const int l = tid & 63, w = tid >> 6;
  const int jl = tid & 7, b0 = tid >> 3;          // pairs: (b0, b0+32) x jl
  const int jg = bk * JPB + jl;

  const float wci = Wci[jg], wcf = Wcf[jg], wco = Wco[jg];
  const float vbi = bi[jg], vbf = bfg[jg], vbc = bc[jg], vbo = bo[jg];

  float cA, cB;
  if (first){ cA = c0g[b0 * Hh + jg]; cB = c0g[(b0 + 32) * Hh + jg]; }
  else      { cA = c_state[b0 * Hh + jg]; cB = c_state[(b0 + 32) * Hh + jg]; }

  // --- W_h fragments: volatile asm loads -> must stay register-resident ---
  h16x8 bfr[32];
  {
    const u32x4* p = Wr + (size_t)bk * 2048 + l;
    #pragma unroll
    for (int pk = 0; pk < 32; ++pk){
      u32x4 t = load_once16(p + (size_t)pk * 64);
      bfr[pk] = *(h16x8*)&t;
    }
    asm volatile("s_waitcnt vmcnt(0)" ::: "memory");
  }

  // --- zx prologue: thread (bz, gz) owns an 8-float gate run ---
  const int bz = tid >> 2, gz = tid & 3;
  const float* zxbase = zx + (size_t)bz * Tc * G4 + gz * 512 + bk * JPB;
  float4 zc0 = *(const float4*)(zxbase);
  float4 zc1 = *(const float4*)(zxbase + 4);

  const int arow = w * 16 + (l & 15);
  const int acol = (l >> 4) * 8;
  const int crow = w * 16 + (l >> 4) * 4;

  for (int s = 0; s < Tc; ++s){
    const int gs = t0 + s;
    const int par = gs & 1;

    // prefetch next step's zx (plain, L2-cached)
    float4 zn0, zn1;
    if (s + 1 < Tc){
      const float* p = zxbase + (size_t)(s + 1) * G4;
      zn0 = *(const float4*)p; zn1 = *(const float4*)(p + 4);
    }

    // wait for all producer blocks of step gs-1 (all-lane poll, no barrier)
    if (gs > 0){
      const unsigned need = (unsigned)gs;
      for (;;){
        unsigned f = load_coh4_wait(flag + l);
        if (__all((int)(f >= need))) break;
      }
    }

    // coherent h loads, overlap with szp staging
    u32x4 hr[16];
    const h16* hp = hbuf + par * (Bb * Hh) + arow * Hh + acol;
    #pragma unroll
    for (int pk = 0; pk < 16; ++pk)
      hr[pk] = load_coh16(hp + pk * 32);

    *(float4*)&szp[bz * 36 + gz * 8]     = zc0;
    *(float4*)&szp[bz * 36 + gz * 8 + 4] = zc1;

    asm volatile("s_waitcnt vmcnt(8)" ::: "memory");
    __builtin_amdgcn_sched_barrier(0);
    f32x4 acc0 = {0.f,0.f,0.f,0.f}, acc1 = {0.f,0.f,0.f,0.f};
    #pragma unroll
    for (int pk = 0; pk < 8; ++pk){
      h16x8 a = *(h16x8*)&hr[pk];
      acc0 = __builtin_amdgcn_mfma_f32_16x16x32_f16(a, bfr[pk],      acc0, 0, 0, 0);
      acc1 = __builtin_amdgcn_mfma_f32_16x16x32_f16(a, bfr[16 + pk], acc1, 0, 0, 0);
    }
    asm volatile("s_waitcnt vmcnt(0)" ::: "memory");
    __builtin_amdgcn_sched_barrier(0);
    #pragma unroll
    for (int pk = 8; pk < 16; ++pk){
      h16x8 a = *(h16x8*)&hr[pk];
      acc0 = __builtin_amdgcn_mfma_f32_16x16x32_f16(a, bfr[pk],      acc0, 0, 0, 0);
      acc1 = __builtin_amdgcn_mfma_f32_16x16x32_f16(a, bfr[16 + pk], acc1, 0, 0, 0);
    }

    // z partials -> LDS  (C layout: row=(l>>4)*4+q, col=l&15)
    #pragma unroll
    for (int q = 0; q < 4; ++q){
      zf[(crow + q) * 33 + (l & 15)]      = acc0[q];
      zf[(crow + q) * 33 + 16 + (l & 15)] = acc1[q];
    }
    __syncthreads();                                    // (1)

    // gates for the 2 (b, jl) pairs; h stored coherent directly
    h16* hdst = hbuf + (par ^ 1) * (Bb * Hh);
    #pragma unroll
    for (int pr = 0; pr < 2; ++pr){
      const int b = b0 + pr * 32;
      float cp = pr ? cB : cA;
      float z_i = szp[b * 36 + jl]      + zf[b * 33 + jl];
      float z_f = szp[b * 36 + 8 + jl]  + zf[b * 33 + 8 + jl];
      float z_c = szp[b * 36 + 16 + jl] + zf[b * 33 + 16 + jl];
      float z_o = szp[b * 36 + 24 + jl] + zf[b * 33 + 24 + jl];
      float iv = sigm(z_i + cp * wci + vbi);
      float fv = sigm(z_f + cp * wcf + vbf);
      float cn = fv * cp + iv * tanh_(z_c + vbc);
      float ov = sigm(z_o + cn * wco + vbo);
      float hn = ov * tanh_(cn);
      if (pr) cB = cn; else cA = cn;
      h16 hh = (h16)hn;
      unsigned hbits = (unsigned)*(unsigned short*)&hh;
      store_coh2(hdst + b * Hh + jg, hbits);
      out[((size_t)b * Ss + gs) * Hh + jg] = hn;
      if (last && s == Tc - 1){ hT[b * Hh + jg] = hn; cT[b * Hh + jg] = cn; }
    }

    asm volatile("s_waitcnt vmcnt(0)" ::: "memory");    // h at coherence point
    __syncthreads();                                    // (2) block-wide drain
    if (tid == 0) store_coh4(flag + bk, (unsigned)(gs + 1));

    zc0 = zn0; zc1 = zn1;
  }

  c_state[b0 * Hh + jg] = cA;
  c_state[(b0 + 32) * Hh + jg] = cB;
}

// ---------------------------------------------------------------------------
extern "C" void kernel_launch(void* const* d_in, const int* in_sizes, int n_in,
                              void* d_out, int out_size, void* d_ws, size_t ws_size,
                              hipStream_t stream){
  const float* x   = (const float*)d_in[0];
  const float* h0  = (const float*)d_in[1];
  const float* c0  = (const float*)d_in[2];
  const float* Wxh = (const float*)d_in[3];
  const float* Wci = (const float*)d_in[4];
  const float* Wcf = (const float*)d_in[5];
  const float* Wco = (const float*)d_in[6];
  const float* bi  = (const float*)d_in[7];
  const float* bf  = (const float*)d_in[8];
  const float* bc  = (const float*)d_in[9];
  const float* bo  = (const float*)d_in[10];

  float* out = (float*)d_out;
  float* hT  = out + (size_t)Bb * Ss * Hh;
  float* cT  = hT + (size_t)Bb * Hh;

  uint8_t* ws = (uint8_t*)d_ws;
  size_t off = 0;
  auto take = [&](size_t bytes) -> uint8_t* {
    uint8_t* p = ws + off;
    off += (bytes + 255) & ~(size_t)255;
    return p;
  };
  h16*      WxT     = (h16*)take((size_t)G4 * Ii * 2);
  u32x4*    Wr      = (u32x4*)take((size_t)G4 * Hh * 2);
  h16*      hbuf    = (h16*)take((size_t)2 * Bb * Hh * 2);
  unsigned* flag    = (unsigned*)take((size_t)NBK * 4);
  float*    c_state = (float*)take((size_t)Bb * Hh * 4);

  int Tc = Ss, tclog = 10;
  while (Tc > 2 && off + (size_t)Bb * Tc * G4 * 4 > ws_size){ Tc >>= 1; tclog--; }
  float* zxbuf = (float*)take((size_t)Bb * Tc * G4 * 4);

  prep_weights<<<(Ii * G4) / 256, 256, 0, stream>>>(Wxh, WxT);
  prep_rec<<<516, 256, 0, stream>>>(Wxh, Wr, h0, hbuf, flag);

  int nch = Ss / Tc;
  for (int c = 0; c < nch; ++c){
    int t0 = c * Tc;
    dim3 grid(G4 / BN, Bb * Tc / BM);
    gemm_zx<<<grid, 256, 0, stream>>>(x, WxT, zxbuf, t0, tclog);
    lstm_rec2<<<NBK, 256, 0, stream>>>(zxbuf, Wr, hbuf, flag, c0, c_state,
                                       Wci, Wcf, Wco, bi, bf, bc, bo,
                                       out, hT, cT, t0, Tc, c == 0, c == nch - 1);
  }
}

// Round 6
// 5030.987 us; speedup vs baseline: 1.1252x; 1.1252x over previous
//
#include <hip/hip_runtime.h>
#include <hip/hip_fp16.h>
#include <stdint.h>
#include <stddef.h>

#define Bb 64
#define Ss 1024
#define Ii 512
#define Hh 512
#define G4 2048   // 4*H
#define NBK 64    // recurrence blocks
#define JPB 8     // hidden units per block

typedef _Float16 h16;
typedef _Float16 h16x8 __attribute__((ext_vector_type(8)));
typedef float    f32x4 __attribute__((ext_vector_type(4)));
typedef unsigned u32x4 __attribute__((ext_vector_type(4)));   // native, asm-legal

__device__ __forceinline__ float sigm(float x){ return 1.0f / (1.0f + __expf(-x)); }
__device__ __forceinline__ float tanh_(float x){
  float e = __expf(-2.0f * fabsf(x));
  float t = (1.0f - e) / (1.0f + e);
  return copysignf(t, x);
}

// device-coherent accesses: bypass L1+L2, served at device coherence point
__device__ __forceinline__ u32x4 load_coh16(const void* p){
  u32x4 r;
  asm volatile("global_load_dwordx4 %0, %1, off sc0 sc1"
               : "=v"(r) : "v"(p) : "memory");
  return r;
}
__device__ __forceinline__ void store_coh2(void* p, unsigned v){
  asm volatile("global_store_short %0, %1, off sc0 sc1"
               :: "v"(p), "v"(v) : "memory");
}
// plain (cacheable) 16B load as volatile asm: cannot be rematerialized
__device__ __forceinline__ u32x4 load_once16(const void* p){
  u32x4 r;
  asm volatile("global_load_dwordx4 %0, %1, off"
               : "=v"(r) : "v"(p) : "memory");
  return r;
}

// ---------------------------------------------------------------------------
// prep 1: WxT[n][k] = (f16) W_xh[k][n] for k < I  (B^T layout for gemm_zx)
// ---------------------------------------------------------------------------
__global__ void prep_weights(const float* __restrict__ Wxh, h16* __restrict__ WxT){
  int idx = blockIdx.x * 256 + threadIdx.x;
  if (idx >= Ii * G4) return;
  int k = idx / G4, n = idx % G4;
  WxT[(size_t)n * Ii + k] = (h16)Wxh[idx];
}

// ---------------------------------------------------------------------------
// prep 2: pack W_h into per-block register-fragment order + init both h
// buffers. Buffer0 = h0 with tag-LSB 0; buffer1 = 0x0001 (tag-LSB 1, so the
// gs=1 consumer (expects LSB 0) can never accept stale/poisoned content).
// ---------------------------------------------------------------------------
__global__ void prep_rec(const float* __restrict__ Wxh, u32x4* __restrict__ Wr,
                         const float* __restrict__ h0g,
                         unsigned short* __restrict__ hbuf){
  int blk = blockIdx.x, tid = threadIdx.x;
  if (blk < 512){
    int d  = blk * 256 + tid;
    int l  = d & 63, pk = (d >> 6) & 31, bk = d >> 11;
    int n  = pk >> 4, ks = pk & 15;
    int k  = ks * 32 + (l >> 4) * 8;
    int cl = n * 16 + (l & 15);
    int col = (cl >> 3) * 512 + bk * JPB + (cl & 7);
    h16x8 v;
    #pragma unroll
    for (int e = 0; e < 8; ++e)
      v[e] = (h16)Wxh[(size_t)(Ii + k + e) * G4 + col];
    Wr[d] = *(u32x4*)&v;
  } else {
    int t = (blk - 512) * 256 + tid;    // 0..1023
    #pragma unroll
    for (int i = 0; i < 32; ++i){
      int idx = t * 32 + i;             // covers 64*512 entries per buffer
      h16 v = (h16)h0g[idx];
      unsigned short b = *(unsigned short*)&v;
      hbuf[idx]                 = (unsigned short)(b & 0xFFFEu);  // tag 0
      hbuf[Bb * Hh + idx]       = (unsigned short)0x0001u;        // tag 1
    }
  }
}

// ---------------------------------------------------------------------------
// zx GEMM (unchanged): zx[r][n] = sum_k x_row(r)[k] * W_x[k][n]
// ---------------------------------------------------------------------------
#define BM 128
#define BN 128
#define BK 32
#define LDP 48

__global__ __launch_bounds__(256) void gemm_zx(const float* __restrict__ x,
                                               const h16* __restrict__ WxT,
                                               float* __restrict__ zx,
                                               int t0, int tclog){
  __shared__ h16 lA[BM][LDP];
  __shared__ h16 lB[BN][LDP];
  const int tid  = threadIdx.x;
  const int lane = tid & 63, wid = tid >> 6;
  const int wm = wid >> 1, wn = wid & 1;
  const int bn0 = blockIdx.x * BN, bm0 = blockIdx.y * BM;

  f32x4 acc[4][4] = {};

  const int r_local = tid >> 1;
  const int kh = (tid & 1) * 16;
  const int r = bm0 + r_local;
  const int bidx = r >> tclog;
  const int sc   = r & ((1 << tclog) - 1);
  const float* xrow = x + ((size_t)bidx * Ss + (t0 + sc)) * Ii + kh;

  for (int ks = 0; ks < Ii / BK; ++ks){
    const int k0 = ks * BK;
    __syncthreads();
    {
      const float* p = xrow + k0;
      f32x4 v0 = *(const f32x4*)(p);
      f32x4 v1 = *(const f32x4*)(p + 4);
      f32x4 v2 = *(const f32x4*)(p + 8);
      f32x4 v3 = *(const f32x4*)(p + 12);
      h16x8 o0, o1;
      o0[0]=(h16)v0[0]; o0[1]=(h16)v0[1]; o0[2]=(h16)v0[2]; o0[3]=(h16)v0[3];
      o0[4]=(h16)v1[0]; o0[5]=(h16)v1[1]; o0[6]=(h16)v1[2]; o0[7]=(h16)v1[3];
      o1[0]=(h16)v2[0]; o1[1]=(h16)v2[1]; o1[2]=(h16)v2[2]; o1[3]=(h16)v2[3];
      o1[4]=(h16)v3[0]; o1[5]=(h16)v3[1]; o1[6]=(h16)v3[2]; o1[7]=(h16)v3[3];
      *(h16x8*)&lA[r_local][kh]     = o0;
      *(h16x8*)&lA[r_local][kh + 8] = o1;
    }
    #pragma unroll
    for (int i = 0; i < 2; ++i){
      int flat = i * 256 + tid;
      int nl = flat >> 2, kq = flat & 3;
      u32x4 w = *(const u32x4*)(WxT + ((size_t)(bn0 + nl)) * Ii + k0 + kq * 8);
      *(u32x4*)&lB[nl][kq * 8] = w;
    }
    __syncthreads();
    h16x8 af[4], bfr[4];
    #pragma unroll
    for (int m = 0; m < 4; ++m)
      af[m] = *(const h16x8*)&lA[wm * 64 + m * 16 + (lane & 15)][(lane >> 4) * 8];
    #pragma unroll
    for (int n = 0; n < 4; ++n)
      bfr[n] = *(const h16x8*)&lB[wn * 64 + n * 16 + (lane & 15)][(lane >> 4) * 8];
    #pragma unroll
    for (int m = 0; m < 4; ++m)
      #pragma unroll
      for (int n = 0; n < 4; ++n)
        acc[m][n] = __builtin_amdgcn_mfma_f32_16x16x32_f16(af[m], bfr[n], acc[m][n], 0, 0, 0);
  }
  #pragma unroll
  for (int m = 0; m < 4; ++m){
    int rg = bm0 + wm * 64 + m * 16 + ((lane >> 4) << 2);
    #pragma unroll
    for (int n = 0; n < 4; ++n){
      int cg = bn0 + wn * 64 + n * 16 + (lane & 15);
      #pragma unroll
      for (int q = 0; q < 4; ++q)
        zx[(size_t)(rg + q) * G4 + cg] = acc[m][n][q];
    }
  }
}

// ---------------------------------------------------------------------------
// Recurrence v5: self-validating h exchange. Each h16 carries the step tag
// in its LSB ((gs>>1)&1 distinguishes gs from gs-2 in the same parity
// buffer). No flags, no producer drain, no separate poll: consumers
// speculatively load+MFMA and retry if any tag is stale.
// ---------------------------------------------------------------------------
__global__ __launch_bounds__(256, 1) void lstm_rec2(
    const float* __restrict__ zx, const u32x4* __restrict__ Wr,
    unsigned short* __restrict__ hbuf,
    const float* __restrict__ c0g, float* __restrict__ c_state,
    const float* __restrict__ Wci, const float* __restrict__ Wcf, const float* __restrict__ Wco,
    const float* __restrict__ bi, const float* __restrict__ bfg, const float* __restrict__ bc,
    const float* __restrict__ bo,
    float* __restrict__ out, float* __restrict__ hT, float* __restrict__ cT,
    int t0, int Tc, int first, int last)
{
  __shared__ float zf[64 * 33];
  __shared__ float szp[64 * 36];

  const int bk = blockIdx.x, tid = threadIdx.x;
  const int l = tid & 63, w = tid >> 6;
  const int jl = tid & 7, b0 = tid >> 3;          // pairs: (b0, b0+32) x jl
  const int jg = bk * JPB + jl;

  const float wci = Wci[jg], wcf = Wcf[jg], wco = Wco[jg];
  const float vbi = bi[jg], vbf = bfg[jg], vbc = bc[jg], vbo = bo[jg];

  float cA, cB;
  if (first){ cA = c0g[b0 * Hh + jg]; cB = c0g[(b0 + 32) * Hh + jg]; }
  else      { cA = c_state[b0 * Hh + jg]; cB = c_state[(b0 + 32) * Hh + jg]; }

  // --- W_h fragments (volatile loads; compiler keeps in VGPR/AGPR file) ---
  h16x8 bfr[32];
  {
    const u32x4* p = Wr + (size_t)bk * 2048 + l;
    #pragma unroll
    for (int pk = 0; pk < 32; ++pk){
      u32x4 t = load_once16(p + (size_t)pk * 64);
      bfr[pk] = *(h16x8*)&t;
    }
    asm volatile("s_waitcnt vmcnt(0)" ::: "memory");
  }

  // --- zx prologue: thread (bz, gz) owns an 8-float gate run ---
  const int bz = tid >> 2, gz = tid & 3;
  const float* zxbase = zx + (size_t)bz * Tc * G4 + gz * 512 + bk * JPB;
  float4 zc0 = *(const float4*)(zxbase);
  float4 zc1 = *(const float4*)(zxbase + 4);

  const int arow = w * 16 + (l & 15);
  const int acol = (l >> 4) * 8;
  const int crow = w * 16 + (l >> 4) * 4;

  for (int s = 0; s < Tc; ++s){
    const int gs = t0 + s;
    const int par = gs & 1;

    // prefetch next step's zx (plain, L2-cached)
    float4 zn0, zn1;
    if (s + 1 < Tc){
      const float* p = zxbase + (size_t)(s + 1) * G4;
      zn0 = *(const float4*)p; zn1 = *(const float4*)(p + 4);
    }

    // stage zx into LDS (guarded by barrier (2) of previous iteration)
    *(float4*)&szp[bz * 36 + gz * 8]     = zc0;
    *(float4*)&szp[bz * 36 + gz * 8 + 4] = zc1;

    // --- speculative load + validate + MFMA, retry while stale ---
    const unsigned exp32 = (((unsigned)gs >> 1) & 1u) * 0x00010001u;
    const unsigned short* hp = hbuf + (size_t)par * (Bb * Hh) + arow * Hh + acol;
    f32x4 acc0, acc1;
    for (;;){
      u32x4 hr[16];
      #pragma unroll
      for (int pk = 0; pk < 16; ++pk)
        hr[pk] = load_coh16(hp + pk * 32);
      asm volatile("s_waitcnt vmcnt(0)" ::: "memory");
      __builtin_amdgcn_sched_barrier(0);
      unsigned bad = 0;
      acc0 = (f32x4){0.f,0.f,0.f,0.f};
      acc1 = (f32x4){0.f,0.f,0.f,0.f};
      #pragma unroll
      for (int pk = 0; pk < 16; ++pk){
        u32x4 v = hr[pk];
        bad |= (v[0] ^ exp32) & 0x00010001u;
        bad |= (v[1] ^ exp32) & 0x00010001u;
        bad |= (v[2] ^ exp32) & 0x00010001u;
        bad |= (v[3] ^ exp32) & 0x00010001u;
        h16x8 a = *(h16x8*)&v;
        acc0 = __builtin_amdgcn_mfma_f32_16x16x32_f16(a, bfr[pk],      acc0, 0, 0, 0);
        acc1 = __builtin_amdgcn_mfma_f32_16x16x32_f16(a, bfr[16 + pk], acc1, 0, 0, 0);
      }
      if (__all(bad == 0)) break;
    }

    // z partials -> LDS  (C layout: row=(l>>4)*4+q, col=l&15)
    #pragma unroll
    for (int q = 0; q < 4; ++q){
      zf[(crow + q) * 33 + (l & 15)]      = acc0[q];
      zf[(crow + q) * 33 + 16 + (l & 15)] = acc1[q];
    }
    __syncthreads();                                    // (1)

    // gates for the 2 (b, jl) pairs; h stored coherent with tag LSB
    const unsigned tagn = (((unsigned)(gs + 1) >> 1) & 1u);
    unsigned short* hdst = hbuf + (size_t)(par ^ 1) * (Bb * Hh);
    #pragma unroll
    for (int pr = 0; pr < 2; ++pr){
      const int b = b0 + pr * 32;
      float cp = pr ? cB : cA;
      float z_i = szp[b * 36 + jl]      + zf[b * 33 + jl];
      float z_f = szp[b * 36 + 8 + jl]  + zf[b * 33 + 8 + jl];
      float z_c = szp[b * 36 + 16 + jl] + zf[b * 33 + 16 + jl];
      float z_o = szp[b * 36 + 24 + jl] + zf[b * 33 + 24 + jl];
      float iv = sigm(z_i + cp * wci + vbi);
      float fv = sigm(z_f + cp * wcf + vbf);
      float cn = fv * cp + iv * tanh_(z_c + vbc);
      float ov = sigm(z_o + cn * wco + vbo);
      float hn = ov * tanh_(cn);
      if (pr) cB = cn; else cA = cn;
      h16 hh = (h16)hn;
      unsigned hbits = ((unsigned)*(unsigned short*)&hh & 0xFFFEu) | tagn;
      store_coh2(hdst + b * Hh + jg, hbits);
      out[((size_t)b * Ss + gs) * Hh + jg] = hn;
      if (last && s == Tc - 1){ hT[b * Hh + jg] = hn; cT[b * Hh + jg] = cn; }
    }
    __syncthreads();                                    // (2) protect szp/zf

    zc0 = zn0; zc1 = zn1;
  }

  c_state[b0 * Hh + jg] = cA;
  c_state[(b0 + 32) * Hh + jg] = cB;
}

// ---------------------------------------------------------------------------
extern "C" void kernel_launch(void* const* d_in, const int* in_sizes, int n_in,
                              void* d_out, int out_size, void* d_ws, size_t ws_size,
                              hipStream_t stream){
  const float* x   = (const float*)d_in[0];
  const float* h0  = (const float*)d_in[1];
  const float* c0  = (const float*)d_in[2];
  const float* Wxh = (const float*)d_in[3];
  const float* Wci = (const float*)d_in[4];
  const float* Wcf = (const float*)d_in[5];
  const float* Wco = (const float*)d_in[6];
  const float* bi  = (const float*)d_in[7];
  const float* bf  = (const float*)d_in[8];
  const float* bc  = (const float*)d_in[9];
  const float* bo  = (const float*)d_in[10];

  float* out = (float*)d_out;
  float* hT  = out + (size_t)Bb * Ss * Hh;
  float* cT  = hT + (size_t)Bb * Hh;

  uint8_t* ws = (uint8_t*)d_ws;
  size_t off = 0;
  auto take = [&](size_t bytes) -> uint8_t* {
    uint8_t* p = ws + off;
    off += (bytes + 255) & ~(size_t)255;
    return p;
  };
  h16*            WxT     = (h16*)take((size_t)G4 * Ii * 2);
  u32x4*          Wr      = (u32x4*)take((size_t)G4 * Hh * 2);
  unsigned short* hbuf    = (unsigned short*)take((size_t)2 * Bb * Hh * 2);
  float*          c_state = (float*)take((size_t)Bb * Hh * 4);

  int Tc = Ss, tclog = 10;
  while (Tc > 2 && off + (size_t)Bb * Tc * G4 * 4 > ws_size){ Tc >>= 1; tclog--; }
  float* zxbuf = (float*)take((size_t)Bb * Tc * G4 * 4);

  prep_weights<<<(Ii * G4) / 256, 256, 0, stream>>>(Wxh, WxT);
  prep_rec<<<516, 256, 0, stream>>>(Wxh, Wr, h0, hbuf);

  int nch = Ss / Tc;
  for (int c = 0; c < nch; ++c){
    int t0 = c * Tc;
    dim3 grid(G4 / BN, Bb * Tc / BM);
    gemm_zx<<<grid, 256, 0, stream>>>(x, WxT, zxbuf, t0, tclog);
    lstm_rec2<<<NBK, 256, 0, stream>>>(zxbuf, Wr, hbuf, c0, c_state,
                                       Wci, Wcf, Wco, bi, bf, bc, bo,
                                       out, hT, cT, t0, Tc, c == 0, c == nch - 1);
  }
}

// Round 7
// 3627.337 us; speedup vs baseline: 1.5606x; 1.3870x over previous
//
#include <hip/hip_runtime.h>
#include <hip/hip_fp16.h>
#include <stdint.h>
#include <stddef.h>

#define Bb 64
#define Ss 1024
#define Ii 512
#define Hh 512
#define G4 2048   // 4*H
#define NBK 64    // recurrence blocks
#define JPB 8     // hidden units per block

typedef _Float16 h16;
typedef _Float16 h16x8 __attribute__((ext_vector_type(8)));
typedef float    f32x4 __attribute__((ext_vector_type(4)));
typedef unsigned u32x4 __attribute__((ext_vector_type(4)));   // native, asm-legal

__device__ __forceinline__ float sigm(float x){ return 1.0f / (1.0f + __expf(-x)); }
__device__ __forceinline__ float tanh_(float x){
  float e = __expf(-2.0f * fabsf(x));
  float t = (1.0f - e) / (1.0f + e);
  return copysignf(t, x);
}

// device-coherent accesses: bypass L1+L2, served at device coherence point
__device__ __forceinline__ u32x4 load_coh16(const void* p){
  u32x4 r;
  asm volatile("global_load_dwordx4 %0, %1, off sc0 sc1"
               : "=v"(r) : "v"(p) : "memory");
  return r;
}
__device__ __forceinline__ void store_coh2(void* p, unsigned v){
  asm volatile("global_store_short %0, %1, off sc0 sc1"
               :: "v"(p), "v"(v) : "memory");
}
// plain (cacheable) 16B load as volatile asm: cannot be rematerialized
__device__ __forceinline__ u32x4 load_once16(const void* p){
  u32x4 r;
  asm volatile("global_load_dwordx4 %0, %1, off"
               : "=v"(r) : "v"(p) : "memory");
  return r;
}

// h fragment-order offset: h[b][j] -> ((b>>4)*16 + (j>>5))*512
//                                     + ((b&15)|(((j>>3)&3)<<4))*8 + (j&7)
__device__ __forceinline__ int hfrag_off(int b, int j){
  return ((b >> 4) * 16 + (j >> 5)) * 512 + (((b & 15) | (((j >> 3) & 3) << 4)) << 3) + (j & 7);
}

// ---------------------------------------------------------------------------
// prep 1: WxT[n][k] = (f16) W_xh[k][n] for k < I  (B^T layout for gemm_zx)
// ---------------------------------------------------------------------------
__global__ void prep_weights(const float* __restrict__ Wxh, h16* __restrict__ WxT){
  int idx = blockIdx.x * 256 + threadIdx.x;
  if (idx >= Ii * G4) return;
  int k = idx / G4, n = idx % G4;
  WxT[(size_t)n * Ii + k] = (h16)Wxh[idx];
}

// ---------------------------------------------------------------------------
// prep 2: pack W_h into per-block register-fragment order + init both h
// buffers in MFMA-fragment order. Buffer0 = h0 with tag-LSB 0; buffer1 =
// 0x0001 (tag 1, never accepted by the gs=1 consumer which expects 0).
// ---------------------------------------------------------------------------
__global__ void prep_rec(const float* __restrict__ Wxh, u32x4* __restrict__ Wr,
                         const float* __restrict__ h0g,
                         unsigned short* __restrict__ hbuf){
  int blk = blockIdx.x, tid = threadIdx.x;
  if (blk < 512){
    int d  = blk * 256 + tid;
    int l  = d & 63, pk = (d >> 6) & 31, bk = d >> 11;
    int n  = pk >> 4, ks = pk & 15;
    int k  = ks * 32 + (l >> 4) * 8;
    int cl = n * 16 + (l & 15);
    int col = (cl >> 3) * 512 + bk * JPB + (cl & 7);
    h16x8 v;
    #pragma unroll
    for (int e = 0; e < 8; ++e)
      v[e] = (h16)Wxh[(size_t)(Ii + k + e) * G4 + col];
    Wr[d] = *(u32x4*)&v;
  } else {
    int t = (blk - 512) * 256 + tid;    // 0..1023
    #pragma unroll
    for (int i = 0; i < 32; ++i){
      int idx = t * 32 + i;             // idx = b*512 + j
      int b = idx >> 9, j = idx & 511;
      h16 v = (h16)h0g[idx];
      unsigned short bits = *(unsigned short*)&v;
      int off = hfrag_off(b, j);
      hbuf[off]           = (unsigned short)(bits & 0xFFFEu);  // tag 0
      hbuf[Bb * Hh + off] = (unsigned short)0x0001u;           // tag 1
    }
  }
}

// ---------------------------------------------------------------------------
// zx GEMM (unchanged): zx[r][n] = sum_k x_row(r)[k] * W_x[k][n]
// ---------------------------------------------------------------------------
#define BM 128
#define BN 128
#define BK 32
#define LDP 48

__global__ __launch_bounds__(256) void gemm_zx(const float* __restrict__ x,
                                               const h16* __restrict__ WxT,
                                               float* __restrict__ zx,
                                               int t0, int tclog){
  __shared__ h16 lA[BM][LDP];
  __shared__ h16 lB[BN][LDP];
  const int tid  = threadIdx.x;
  const int lane = tid & 63, wid = tid >> 6;
  const int wm = wid >> 1, wn = wid & 1;
  const int bn0 = blockIdx.x * BN, bm0 = blockIdx.y * BM;

  f32x4 acc[4][4] = {};

  const int r_local = tid >> 1;
  const int kh = (tid & 1) * 16;
  const int r = bm0 + r_local;
  const int bidx = r >> tclog;
  const int sc   = r & ((1 << tclog) - 1);
  const float* xrow = x + ((size_t)bidx * Ss + (t0 + sc)) * Ii + kh;

  for (int ks = 0; ks < Ii / BK; ++ks){
    const int k0 = ks * BK;
    __syncthreads();
    {
      const float* p = xrow + k0;
      f32x4 v0 = *(const f32x4*)(p);
      f32x4 v1 = *(const f32x4*)(p + 4);
      f32x4 v2 = *(const f32x4*)(p + 8);
      f32x4 v3 = *(const f32x4*)(p + 12);
      h16x8 o0, o1;
      o0[0]=(h16)v0[0]; o0[1]=(h16)v0[1]; o0[2]=(h16)v0[2]; o0[3]=(h16)v0[3];
      o0[4]=(h16)v1[0]; o0[5]=(h16)v1[1]; o0[6]=(h16)v1[2]; o0[7]=(h16)v1[3];
      o1[0]=(h16)v2[0]; o1[1]=(h16)v2[1]; o1[2]=(h16)v2[2]; o1[3]=(h16)v2[3];
      o1[4]=(h16)v3[0]; o1[5]=(h16)v3[1]; o1[6]=(h16)v3[2]; o1[7]=(h16)v3[3];
      *(h16x8*)&lA[r_local][kh]     = o0;
      *(h16x8*)&lA[r_local][kh + 8] = o1;
    }
    #pragma unroll
    for (int i = 0; i < 2; ++i){
      int flat = i * 256 + tid;
      int nl = flat >> 2, kq = flat & 3;
      u32x4 w = *(const u32x4*)(WxT + ((size_t)(bn0 + nl)) * Ii + k0 + kq * 8);
      *(u32x4*)&lB[nl][kq * 8] = w;
    }
    __syncthreads();
    h16x8 af[4], bfr[4];
    #pragma unroll
    for (int m = 0; m < 4; ++m)
      af[m] = *(const h16x8*)&lA[wm * 64 + m * 16 + (lane & 15)][(lane >> 4) * 8];
    #pragma unroll
    for (int n = 0; n < 4; ++n)
      bfr[n] = *(const h16x8*)&lB[wn * 64 + n * 16 + (lane & 15)][(lane >> 4) * 8];
    #pragma unroll
    for (int m = 0; m < 4; ++m)
      #pragma unroll
      for (int n = 0; n < 4; ++n)
        acc[m][n] = __builtin_amdgcn_mfma_f32_16x16x32_f16(af[m], bfr[n], acc[m][n], 0, 0, 0);
  }
  #pragma unroll
  for (int m = 0; m < 4; ++m){
    int rg = bm0 + wm * 64 + m * 16 + ((lane >> 4) << 2);
    #pragma unroll
    for (int n = 0; n < 4; ++n){
      int cg = bn0 + wn * 64 + n * 16 + (lane & 15);
      #pragma unroll
      for (int q = 0; q < 4; ++q)
        zx[(size_t)(rg + q) * G4 + cg] = acc[m][n][q];
    }
  }
}

// ---------------------------------------------------------------------------
// Recurrence v6: h exchanged in MFMA-fragment order -> consumer loads are
// fully coalesced (1KB/instruction). Self-validating tag LSB per h16.
// ---------------------------------------------------------------------------
__global__ __launch_bounds__(256, 1) void lstm_rec2(
    const float* __restrict__ zx, const u32x4* __restrict__ Wr,
    unsigned short* __restrict__ hbuf,
    const float* __restrict__ c0g, float* __restrict__ c_state,
    const float* __restrict__ Wci, const float* __restrict__ Wcf, const float* __restrict__ Wco,
    const float* __restrict__ bi, const float* __restrict__ bfg, const float* __restrict__ bc,
    const float* __restrict__ bo,
    float* __restrict__ out, float* __restrict__ hT, float* __restrict__ cT,
    int t0, int Tc, int first, int last)
{
  __shared__ float zf[64 * 33];
  __shared__ float szp[64 * 36];

  const int bk = blockIdx.x, tid = threadIdx.x;
  const int l = tid & 63, w = tid >> 6;
  const int jl = tid & 7, b0 = tid >> 3;          // pairs: (b0, b0+32) x jl
  const int jg = bk * JPB + jl;

  const float wci = Wci[jg], wcf = Wcf[jg], wco = Wco[jg];
  const float vbi = bi[jg], vbf = bfg[jg], vbc = bc[jg], vbo = bo[jg];

  float cA, cB;
  if (first){ cA = c0g[b0 * Hh + jg]; cB = c0g[(b0 + 32) * Hh + jg]; }
  else      { cA = c_state[b0 * Hh + jg]; cB = c_state[(b0 + 32) * Hh + jg]; }

  // --- W_h fragments (volatile loads; live in unified VGPR/AGPR file) ---
  h16x8 bfr[32];
  {
    const u32x4* p = Wr + (size_t)bk * 2048 + l;
    #pragma unroll
    for (int pk = 0; pk < 32; ++pk){
      u32x4 t = load_once16(p + (size_t)pk * 64);
      bfr[pk] = *(h16x8*)&t;
    }
    asm volatile("s_waitcnt vmcnt(0)" ::: "memory");
  }

  // --- zx prologue: thread (bz, gz) owns an 8-float gate run ---
  const int bz = tid >> 2, gz = tid & 3;
  const float* zxbase = zx + (size_t)bz * Tc * G4 + gz * 512 + bk * JPB;
  float4 zc0 = *(const float4*)(zxbase);
  float4 zc1 = *(const float4*)(zxbase + 4);

  const int crow = w * 16 + (l >> 4) * 4;

  // producer-side fragment offsets (block-constant pieces)
  const int st_pk = bk >> 2;                       // j>>5 for this block
  const int st_lhi = (bk & 3) << 4;
  // consumer-side base offset for this wave/lane (within one parity buffer)
  const int ld_off = (w * 16) * 512 + l * 8;

  for (int s = 0; s < Tc; ++s){
    const int gs = t0 + s;
    const int par = gs & 1;

    // prefetch next step's zx (plain, L2-cached)
    float4 zn0, zn1;
    if (s + 1 < Tc){
      const float* p = zxbase + (size_t)(s + 1) * G4;
      zn0 = *(const float4*)p; zn1 = *(const float4*)(p + 4);
    }

    // stage zx into LDS (guarded by barrier (2) of previous iteration)
    *(float4*)&szp[bz * 36 + gz * 8]     = zc0;
    *(float4*)&szp[bz * 36 + gz * 8 + 4] = zc1;

    // --- speculative coalesced load + validate + MFMA, retry while stale ---
    const unsigned exp32 = (((unsigned)gs >> 1) & 1u) * 0x00010001u;
    const unsigned short* hp = hbuf + (size_t)par * (Bb * Hh) + ld_off;
    f32x4 acc0, acc1;
    for (;;){
      u32x4 hr[16];
      #pragma unroll
      for (int pk = 0; pk < 16; ++pk)
        hr[pk] = load_coh16(hp + pk * 512);
      asm volatile("s_waitcnt vmcnt(0)" ::: "memory");
      __builtin_amdgcn_sched_barrier(0);
      unsigned bad = 0;
      acc0 = (f32x4){0.f,0.f,0.f,0.f};
      acc1 = (f32x4){0.f,0.f,0.f,0.f};
      #pragma unroll
      for (int pk = 0; pk < 16; ++pk){
        u32x4 v = hr[pk];
        bad |= (v[0] ^ exp32) & 0x00010001u;
        bad |= (v[1] ^ exp32) & 0x00010001u;
        bad |= (v[2] ^ exp32) & 0x00010001u;
        bad |= (v[3] ^ exp32) & 0x00010001u;
        h16x8 a = *(h16x8*)&v;
        acc0 = __builtin_amdgcn_mfma_f32_16x16x32_f16(a, bfr[pk],      acc0, 0, 0, 0);
        acc1 = __builtin_amdgcn_mfma_f32_16x16x32_f16(a, bfr[16 + pk], acc1, 0, 0, 0);
      }
      if (__all(bad == 0)) break;
    }

    // z partials -> LDS  (C layout: row=(l>>4)*4+q, col=l&15)
    #pragma unroll
    for (int q = 0; q < 4; ++q){
      zf[(crow + q) * 33 + (l & 15)]      = acc0[q];
      zf[(crow + q) * 33 + 16 + (l & 15)] = acc1[q];
    }
    __syncthreads();                                    // (1)

    // gates for the 2 (b, jl) pairs; h stored coherent in fragment order
    const unsigned tagn = (((unsigned)(gs + 1) >> 1) & 1u);
    unsigned short* hdst = hbuf + (size_t)(par ^ 1) * (Bb * Hh);
    #pragma unroll
    for (int pr = 0; pr < 2; ++pr){
      const int b = b0 + pr * 32;
      float cp = pr ? cB : cA;
      float z_i = szp[b * 36 + jl]      + zf[b * 33 + jl];
      float z_f = szp[b * 36 + 8 + jl]  + zf[b * 33 + 8 + jl];
      float z_c = szp[b * 36 + 16 + jl] + zf[b * 33 + 16 + jl];
      float z_o = szp[b * 36 + 24 + jl] + zf[b * 33 + 24 + jl];
      float iv = sigm(z_i + cp * wci + vbi);
      float fv = sigm(z_f + cp * wcf + vbf);
      float cn = fv * cp + iv * tanh_(z_c + vbc);
      float ov = sigm(z_o + cn * wco + vbo);
      float hn = ov * tanh_(cn);
      if (pr) cB = cn; else cA = cn;
      h16 hh = (h16)hn;
      unsigned hbits = ((unsigned)*(unsigned short*)&hh & 0xFFFEu) | tagn;
      int off = ((b >> 4) * 16 + st_pk) * 512 + (((b & 15) | st_lhi) << 3) + jl;
      store_coh2(hdst + off, hbits);
      out[((size_t)b * Ss + gs) * Hh + jg] = hn;
      if (last && s == Tc - 1){ hT[b * Hh + jg] = hn; cT[b * Hh + jg] = cn; }
    }
    __syncthreads();                                    // (2) protect szp/zf

    zc0 = zn0; zc1 = zn1;
  }

  c_state[b0 * Hh + jg] = cA;
  c_state[(b0 + 32) * Hh + jg] = cB;
}

// ---------------------------------------------------------------------------
extern "C" void kernel_launch(void* const* d_in, const int* in_sizes, int n_in,
                              void* d_out, int out_size, void* d_ws, size_t ws_size,
                              hipStream_t stream){
  const float* x   = (const float*)d_in[0];
  const float* h0  = (const float*)d_in[1];
  const float* c0  = (const float*)d_in[2];
  const float* Wxh = (const float*)d_in[3];
  const float* Wci = (const float*)d_in[4];
  const float* Wcf = (const float*)d_in[5];
  const float* Wco = (const float*)d_in[6];
  const float* bi  = (const float*)d_in[7];
  const float* bf  = (const float*)d_in[8];
  const float* bc  = (const float*)d_in[9];
  const float* bo  = (const float*)d_in[10];

  float* out = (float*)d_out;
  float* hT  = out + (size_t)Bb * Ss * Hh;
  float* cT  = hT + (size_t)Bb * Hh;

  uint8_t* ws = (uint8_t*)d_ws;
  size_t off = 0;
  auto take = [&](size_t bytes) -> uint8_t* {
    uint8_t* p = ws + off;
    off += (bytes + 255) & ~(size_t)255;
    return p;
  };
  h16*            WxT     = (h16*)take((size_t)G4 * Ii * 2);
  u32x4*          Wr      = (u32x4*)take((size_t)G4 * Hh * 2);
  unsigned short* hbuf    = (unsigned short*)take((size_t)2 * Bb * Hh * 2);
  float*          c_state = (float*)take((size_t)Bb * Hh * 4);

  int Tc = Ss, tclog = 10;
  while (Tc > 2 && off + (size_t)Bb * Tc * G4 * 4 > ws_size){ Tc >>= 1; tclog--; }
  float* zxbuf = (float*)take((size_t)Bb * Tc * G4 * 4);

  prep_weights<<<(Ii * G4) / 256, 256, 0, stream>>>(Wxh, WxT);
  prep_rec<<<516, 256, 0, stream>>>(Wxh, Wr, h0, hbuf);

  int nch = Ss / Tc;
  for (int c = 0; c < nch; ++c){
    int t0 = c * Tc;
    dim3 grid(G4 / BN, Bb * Tc / BM);
    gemm_zx<<<grid, 256, 0, stream>>>(x, WxT, zxbuf, t0, tclog);
    lstm_rec2<<<NBK, 256, 0, stream>>>(zxbuf, Wr, hbuf, c0, c_state,
                                       Wci, Wcf, Wco, bi, bf, bc, bo,
                                       out, hT, cT, t0, Tc, c == 0, c == nch - 1);
  }
}